// Round 7
// baseline (46.571 us; speedup 1.0000x reference)
//
#include <hip/hip_runtime.h>
#include <stdint.h>

#define NB 256
#define NQ 900
#define NC 256
#define TOPK 100
#define QC (NQ * NC)      // 230400
#define NBINS_S 4096
#define CAP 4096
#define BCAP 2048         // per-block stage in kB
#define FCAP 512
#define KS 25
#define SHIFT 18

// ---- workspace layout (4-byte words) ----
#define W_THR   0                       // 256: thrBits per image
#define W_NACT  256                     // 256: nActive per image
#define W_CCNT  512                     // 256: candidate count per image
#define W_OVF   768                     // 256: stage-overflow flag per image
#define W_EOBJ  1024                    // 256*900 floats
#define W_AQ    (W_EOBJ + NB * NQ)      // 256*900 uints
#define W_CAND  (W_AQ + NB * NQ)        // 256*CAP int2 (bits, idx)

__device__ __forceinline__ float fastsig(float x) {
    return __builtin_amdgcn_rcpf(1.0f + __expf(-x));
}

// =================== kernel A: threshold + active rows ===================
__global__ __launch_bounds__(1024)
void kA(const float* __restrict__ obj, const float* __restrict__ logits,
        unsigned* __restrict__ wsu, float* __restrict__ wsf)
{
    const int b = blockIdx.x;
    const int tid = threadIdx.x;
    const int wid = tid >> 6;
    const int lane = tid & 63;

    __shared__ unsigned shist[NBINS_S];
    __shared__ float eobj[NQ];
    __shared__ unsigned part[1024];
    __shared__ unsigned part2[32];
    __shared__ int s_thrBin, s_nActive;

    if (tid == 0) { wsu[W_CCNT + b] = 0u; wsu[W_OVF + b] = 0u; s_nActive = 0; }
    for (int i = tid; i < NBINS_S; i += 1024) shist[i] = 0;
    for (int i = tid; i < NQ; i += 1024) {
        float e = expf(-obj[b * NQ + i]);     // PRECISE (defines outputs)
        eobj[i] = e;
        wsf[W_EOBJ + b * NQ + i] = e;
    }
    __syncthreads();

    const float4* lg4 = (const float4*)(logits + (size_t)b * QC);

    // sampled histogram: 56 rows (1/16), wave per row, fast math (threshold only)
    for (int j = wid; j < 56; j += 16) {
        int q = j * 16 + 8;
        if (lane < 60) {
            float eo = eobj[q];
            float4 v = lg4[(q << 6) + lane];
            atomicAdd(&shist[__float_as_uint(eo * fastsig(v.x)) >> SHIFT], 1u);
            atomicAdd(&shist[__float_as_uint(eo * fastsig(v.y)) >> SHIFT], 1u);
            atomicAdd(&shist[__float_as_uint(eo * fastsig(v.z)) >> SHIFT], 1u);
            atomicAdd(&shist[__float_as_uint(eo * fastsig(v.w)) >> SHIFT], 1u);
        }
    }
    __syncthreads();

    // hierarchical reduce + serial walk (R3-proven)
    {
        unsigned sum = 0;
        #pragma unroll
        for (int j = 0; j < 4; ++j) sum += shist[tid * 4 + j];
        part[tid] = sum;
    }
    __syncthreads();
    if (tid < 32) {
        unsigned s2 = 0;
        #pragma unroll
        for (int j = 0; j < 32; ++j) s2 += part[tid * 32 + j];
        part2[tid] = s2;
    }
    __syncthreads();
    if (tid == 0) {
        int cum = 0;
        int sc = 31;
        while (sc > 0 && cum + (int)part2[sc] < KS) { cum += (int)part2[sc]; --sc; }
        int pc = sc * 32 + 31, plo = sc * 32;
        while (pc > plo && cum + (int)part[pc] < KS) { cum += (int)part[pc]; --pc; }
        int bin = pc * 4 + 3, blo = pc * 4;
        while (bin > blo && cum + (int)shist[bin] < KS) { cum += (int)shist[bin]; --bin; }
        s_thrBin = bin;
    }
    __syncthreads();
    const unsigned thrBits = (unsigned)s_thrBin << SHIFT;
    if (tid == 0) wsu[W_THR + b] = thrBits;

    // active rows (exact bound: score <= eobj)
    if (tid < NQ && __float_as_uint(eobj[tid]) >= thrBits) {
        int p = atomicAdd(&s_nActive, 1);
        wsu[W_AQ + b * NQ + p] = (unsigned)tid;
    }
    __syncthreads();
    if (tid == 0) wsu[W_NACT + b] = (unsigned)s_nActive;
}

// =================== kernel B: collect candidates (4 blocks/image) ===================
__global__ __launch_bounds__(256)
void kB(const float* __restrict__ logits, unsigned* __restrict__ wsu,
        const float* __restrict__ wsf)
{
    const int blk = blockIdx.x;
    const int b = blk >> 2;
    const int s = blk & 3;
    const int tid = threadIdx.x;
    const int w = tid >> 6;
    const int lane = tid & 63;

    __shared__ int2 stage[BCAP];        // 16 KB
    __shared__ int s_local, s_base;

    if (tid == 0) s_local = 0;
    __syncthreads();

    const unsigned thrBits = wsu[W_THR + b];
    const int nA = (int)wsu[W_NACT + b];
    const float4* lg4 = (const float4*)(logits + (size_t)b * QC);
    const int g = s * 4 + w;            // global wave id within image: 0..15

    for (int j = g; j < nA; j += 16) {
        int q = (int)wsu[W_AQ + b * NQ + j];        // uniform -> broadcast
        float eo = wsf[W_EOBJ + b * NQ + q];        // uniform -> broadcast
        float4 v = make_float4(0.f, 0.f, 0.f, 0.f);
        bool ok = (lane < 60);
        if (ok) v = lg4[(q << 6) + lane];
        #pragma unroll
        for (int j2 = 0; j2 < 4; ++j2) {
            float x = (j2 == 0) ? v.x : (j2 == 1) ? v.y : (j2 == 2) ? v.z : v.w;
            float sc = eo * (1.0f / (1.0f + expf(-x)));   // PRECISE (defines outputs)
            unsigned bits = __float_as_uint(sc);
            if (ok && bits >= thrBits) {
                int p = atomicAdd(&s_local, 1);
                if (p < BCAP) stage[p] = make_int2((int)bits, (q << 8) + (lane << 2) + j2);
            }
        }
    }
    __syncthreads();

    const int loc = s_local;
    const int put = min(loc, BCAP);
    if (tid == 0) {
        s_base = (int)atomicAdd(&wsu[W_CCNT + b], (unsigned)put);
        if (loc > BCAP) atomicOr(&wsu[W_OVF + b], 1u);
    }
    __syncthreads();
    const int base = s_base;
    int2* cand = (int2*)(wsu + W_CAND);
    for (int i = tid; i < put; i += 256) {
        int p = base + i;
        if (p < CAP) cand[b * CAP + p] = stage[i];
    }
}

// =================== kernel C: exact select + output ===================
__global__ __launch_bounds__(1024)
void kC(const float* __restrict__ logits, const float* __restrict__ pboxes,
        const float* __restrict__ tsz, float* __restrict__ out,
        unsigned* __restrict__ wsu, const float* __restrict__ wsf)
{
    const int b = blockIdx.x;
    const int tid = threadIdx.x;
    const int wid = tid >> 6;
    const int lane = tid & 63;

    __shared__ unsigned cbits[CAP];     // 16 KB
    __shared__ int cidx[CAP];           // 16 KB
    __shared__ float eobj[NQ];          // fallback only
    __shared__ unsigned rhist[256], rsuf[256];
    __shared__ unsigned fbv[FCAP];
    __shared__ int fiv[FCAP];
    __shared__ int s_cnt, s_c2, s_dig, s_above, s_nfin;

    unsigned thrBits = wsu[W_THR + b];
    const int Mraw = (int)wsu[W_CCNT + b];
    const int ovf = (int)wsu[W_OVF + b];
    const float4* lg4 = (const float4*)(logits + (size_t)b * QC);
    const int2* cand = (const int2*)(wsu + W_CAND);
    int M;

    if (Mraw >= TOPK && Mraw <= CAP && !ovf) {
        M = Mraw;
        for (int i = tid; i < M; i += 1024) {
            int2 cc = cand[b * CAP + i];
            cbits[i] = (unsigned)cc.x;
            cidx[i] = cc.y;
        }
        __syncthreads();
    } else {
        // fallback (exact, any data): binary-search threshold, full rescan
        for (int i = tid; i < NQ; i += 1024) eobj[i] = wsf[W_EOBJ + b * NQ + i];
        if (tid == 0) s_cnt = 0;
        __syncthreads();
        int lo = 0, hi = NBINS_S - 1;
        while (lo < hi) {
            int mid = (lo + hi + 1) >> 1;
            unsigned tb = (unsigned)mid << SHIFT;
            if (tid == 0) s_c2 = 0;
            __syncthreads();
            int local = 0;
            for (int j = wid; j < NQ; j += 16) {
                if (__float_as_uint(eobj[j]) >= tb && lane < 60) {
                    float eo = eobj[j];
                    float4 v = lg4[(j << 6) + lane];
                    local += (__float_as_uint(eo * (1.0f / (1.0f + expf(-v.x)))) >= tb);
                    local += (__float_as_uint(eo * (1.0f / (1.0f + expf(-v.y)))) >= tb);
                    local += (__float_as_uint(eo * (1.0f / (1.0f + expf(-v.z)))) >= tb);
                    local += (__float_as_uint(eo * (1.0f / (1.0f + expf(-v.w)))) >= tb);
                }
            }
            atomicAdd(&s_c2, local);
            __syncthreads();
            if (s_c2 >= TOPK) lo = mid; else hi = mid - 1;
            __syncthreads();
        }
        unsigned tb = (unsigned)lo << SHIFT;
        thrBits = tb;
        __syncthreads();
        for (int j = wid; j < NQ; j += 16) {
            if (__float_as_uint(eobj[j]) >= tb && lane < 60) {
                float eo = eobj[j];
                float4 v = lg4[(j << 6) + lane];
                #pragma unroll
                for (int j2 = 0; j2 < 4; ++j2) {
                    float x = (j2 == 0) ? v.x : (j2 == 1) ? v.y : (j2 == 2) ? v.z : v.w;
                    float sc = eo * (1.0f / (1.0f + expf(-x)));
                    unsigned bits = __float_as_uint(sc);
                    if (bits >= tb) {
                        int p = atomicAdd(&s_cnt, 1);
                        if (p < CAP) { cbits[p] = bits; cidx[p] = (j << 8) + (lane << 2) + j2; }
                    }
                }
            }
        }
        __syncthreads();
        M = min(s_cnt, CAP);
    }

    // ---- radix-select: exact TOPK-th largest among cbits[0..M) ----
    unsigned prefixVal = 0;
    int need = TOPK;
    int startShift = 24;
    if ((thrBits >> 24) == 0x3Fu) { prefixVal = 0x3F000000u; startShift = 16; }
    for (int shift = startShift; shift >= 0; shift -= 8) {
        if (tid < 256) rhist[tid] = 0;
        __syncthreads();
        unsigned pmask = (shift >= 24) ? 0u : (0xFFFFFFFFu << (shift + 8));
        for (int i = tid; i < M; i += 1024) {
            unsigned bb = cbits[i];
            if ((bb & pmask) == (prefixVal & pmask))
                atomicAdd(&rhist[(bb >> shift) & 255], 1u);
        }
        __syncthreads();
        if (tid < 64) {
            unsigned h0 = rhist[tid * 4 + 0];
            unsigned h1 = rhist[tid * 4 + 1];
            unsigned h2 = rhist[tid * 4 + 2];
            unsigned h3 = rhist[tid * 4 + 3];
            unsigned loc = h0 + h1 + h2 + h3;
            unsigned suf = loc;
            #pragma unroll
            for (int d = 1; d < 64; d <<= 1) {
                unsigned o = __shfl_down(suf, d);
                suf += (tid + d < 64) ? o : 0u;
            }
            unsigned above = suf - loc;
            rsuf[tid * 4 + 3] = above + h3;
            rsuf[tid * 4 + 2] = above + h3 + h2;
            rsuf[tid * 4 + 1] = above + h3 + h2 + h1;
            rsuf[tid * 4 + 0] = above + h3 + h2 + h1 + h0;
        }
        __syncthreads();
        if (tid < 256) {
            int sv = (int)rsuf[tid];
            int sa = (tid == 255) ? 0 : (int)rsuf[tid + 1];
            if (sv >= need && sa < need) { s_dig = tid; s_above = sa; }
        }
        __syncthreads();
        prefixVal |= ((unsigned)s_dig) << shift;
        need -= s_above;
    }
    const unsigned kth = prefixVal;

    // ---- compact survivors ----
    if (tid == 0) s_nfin = 0;
    __syncthreads();
    for (int i = tid; i < M; i += 1024) {
        unsigned bb = cbits[i];
        if (bb >= kth) {
            int p = atomicAdd(&s_nfin, 1);
            if (p < FCAP) { fbv[p] = bb; fiv[p] = cidx[i]; }
        }
    }
    __syncthreads();
    const int n = min(s_nfin, FCAP);

    // ---- exact rank (desc bits, tie -> lower index) + output ----
    const float ih = tsz[b * 2 + 0];
    const float iw = tsz[b * 2 + 1];
    float* out_scores = out;
    float* out_labels = out + NB * TOPK;
    float* out_boxes  = out + 2 * NB * TOPK;

    for (int i = tid; i < n; i += 1024) {
        unsigned mb = fbv[i];
        int mi = fiv[i];
        int rank = 0;
        for (int j = 0; j < n; ++j) {
            unsigned ob = fbv[j];
            int oi = fiv[j];
            rank += (ob > mb) || (ob == mb && oi < mi);
        }
        if (rank < TOPK) {
            int q = mi >> 8;
            int c = mi & 255;
            out_scores[b * TOPK + rank] = __uint_as_float(mb);
            out_labels[b * TOPK + rank] = (float)c;
            const float* bp = pboxes + ((size_t)b * NQ + q) * 4;
            float cx = bp[0], cy = bp[1], w = bp[2], h = bp[3];
            float* dst = out_boxes + ((size_t)b * TOPK + rank) * 4;
            dst[0] = (cx - 0.5f * w) * iw;
            dst[1] = (cy - 0.5f * h) * ih;
            dst[2] = (cx + 0.5f * w) * iw;
            dst[3] = (cy + 0.5f * h) * ih;
        }
    }
}

extern "C" void kernel_launch(void* const* d_in, const int* in_sizes, int n_in,
                              void* d_out, int out_size, void* d_ws, size_t ws_size,
                              hipStream_t stream) {
    const float* logits = (const float*)d_in[0];
    const float* obj    = (const float*)d_in[1];
    const float* boxes  = (const float*)d_in[2];
    const float* tsz    = (const float*)d_in[3];
    float* out = (float*)d_out;
    unsigned* wsu = (unsigned*)d_ws;
    float* wsf = (float*)d_ws;

    hipLaunchKernelGGL(kA, dim3(NB), dim3(1024), 0, stream, obj, logits, wsu, wsf);
    hipLaunchKernelGGL(kB, dim3(NB * 4), dim3(256), 0, stream, logits, wsu, wsf);
    hipLaunchKernelGGL(kC, dim3(NB), dim3(1024), 0, stream,
                       logits, boxes, tsz, out, wsu, wsf);
}